// Round 1
// baseline (23092.804 us; speedup 1.0000x reference)
//
#include <hip/hip_runtime.h>
#include <hip/hip_bf16.h>
#include <math.h>

// Problem constants
#define SCALE_ 0.125f   // 1/sqrt(64)

__device__ __forceinline__ float dot4(float4 a, float4 b) {
  return a.x * b.x + a.y * b.y + a.z * b.z + a.w * b.w;
}

// ---------------------------------------------------------------------------
// Generic tiled f32 GEMM: C[M,N] = A[M,K] @ B[K,N]
// A rows come from A0 (r < split) or A1 (r >= split) -- handles concat(mem,x).
// M,N multiples of 64; K multiple of 16.
// ---------------------------------------------------------------------------
#define BM 64
#define BN 64
#define BKK 16

__global__ __launch_bounds__(256) void gemm_f32(
    const float* __restrict__ A0, const float* __restrict__ A1, int split,
    const float* __restrict__ B, float* __restrict__ C,
    int M, int N, int K)
{
  __shared__ float As[BKK][BM + 4];
  __shared__ float Bs[BKK][BN];
  const int bn = blockIdx.x * BN;
  const int bm = blockIdx.y * BM;
  const int tid = threadIdx.x;
  const int tm = (tid >> 4) << 2;   // 0..60
  const int tn = (tid & 15) << 2;   // 0..60
  const int ar = tid >> 2;          // 0..63
  const int ak = (tid & 3) << 2;    // 0,4,8,12
  const int br = tid >> 4;          // 0..15
  const int bc = (tid & 15) << 2;   // 0..60

  const int r = bm + ar;
  const float* Arow = (r < split) ? (A0 + (size_t)r * K)
                                  : (A1 + (size_t)(r - split) * K);
  float acc[4][4] = {};

  for (int k0 = 0; k0 < K; k0 += BKK) {
    float4 a4 = *(const float4*)(Arow + k0 + ak);
    float4 b4 = *(const float4*)(B + (size_t)(k0 + br) * N + bn + bc);
    As[ak + 0][ar] = a4.x;
    As[ak + 1][ar] = a4.y;
    As[ak + 2][ar] = a4.z;
    As[ak + 3][ar] = a4.w;
    *(float4*)&Bs[br][bc] = b4;
    __syncthreads();
#pragma unroll
    for (int k = 0; k < BKK; ++k) {
      float4 av = *(const float4*)&As[k][tm];
      float4 bv = *(const float4*)&Bs[k][tn];
      float aa[4] = {av.x, av.y, av.z, av.w};
      float bb[4] = {bv.x, bv.y, bv.z, bv.w};
#pragma unroll
      for (int i = 0; i < 4; ++i)
#pragma unroll
        for (int j = 0; j < 4; ++j)
          acc[i][j] = fmaf(aa[i], bb[j], acc[i][j]);
    }
    __syncthreads();
  }

#pragma unroll
  for (int i = 0; i < 4; ++i) {
    *(float4*)(C + (size_t)(bm + tm + i) * N + bn + tn) =
        make_float4(acc[i][0], acc[i][1], acc[i][2], acc[i][3]);
  }
}

// ---------------------------------------------------------------------------
// Fused attention.
// Grid: (16 i-blocks, 4 b, 8 n). Block: 256 threads.
// Per WG: queries i0..i0+31 for fixed (b,n).
// score(i,t) = [ (qu_i . k_t) * gate[i, t>>9]
//              + (qv_i . rel_{t+511-i}) * gate[i, (t+511-i)>>9] ] * SCALE,
// masked (-inf) when t > 1536 + i  (== rel-shift garbage region).
// Pass 1: online row max m and denom l. Pass 2: recompute scores -> prob,
// atomicAdd prob/32 into attn_matrix, accumulate PV into vec.
// ---------------------------------------------------------------------------
struct AttnSmem {
  float Qu[32][68];
  float Qv[32][68];
  float Ks[64][68];   // K tile; reused for V tile in pass 2
  float Rs[96][68];   // rel rows rbase..rbase+95
  float sb[32][66];   // scores / probs
  float gates[32][4];
  float mrow[32];
  float lrow[32];
};

__device__ __forceinline__ void attn_scores(
    AttnSmem& sm, int i0, int tbase, int tq, int tt)
{
  float sAC[4][2] = {};
  float sBD[4][2] = {};
#pragma unroll
  for (int d0 = 0; d0 < 64; d0 += 4) {
    float4 k0 = *(const float4*)&sm.Ks[tt][d0];
    float4 k1 = *(const float4*)&sm.Ks[tt + 1][d0];
#pragma unroll
    for (int qq = 0; qq < 4; ++qq) {
      const int ql = (tq << 2) + qq;
      float4 qu = *(const float4*)&sm.Qu[ql][d0];
      float4 qv = *(const float4*)&sm.Qv[ql][d0];
      const int row0 = tt + 31 - ql;   // in [0,94]
      float4 r0 = *(const float4*)&sm.Rs[row0][d0];
      float4 r1 = *(const float4*)&sm.Rs[row0 + 1][d0];
      sAC[qq][0] += dot4(qu, k0);
      sAC[qq][1] += dot4(qu, k1);
      sBD[qq][0] += dot4(qv, r0);
      sBD[qq][1] += dot4(qv, r1);
    }
  }
#pragma unroll
  for (int qq = 0; qq < 4; ++qq) {
    const int ql = (tq << 2) + qq;
    const int i = i0 + ql;
#pragma unroll
    for (int ti = 0; ti < 2; ++ti) {
      const int tg = tbase + tt + ti;
      float s;
      if (tg > 1536 + i) {
        s = -INFINITY;
      } else {
        const int rr = tg + 511 - i;
        s = (sAC[qq][ti] * sm.gates[ql][tg >> 9] +
             sBD[qq][ti] * sm.gates[ql][rr >> 9]) * SCALE_;
      }
      sm.sb[ql][tt + ti] = s;
    }
  }
}

__global__ __launch_bounds__(256) void attn_f32(
    const float* __restrict__ qb, const float* __restrict__ kvb,
    const float* __restrict__ relb, const float* __restrict__ pbu,
    const float* __restrict__ pbv, const float* __restrict__ indice,
    float* __restrict__ vecb, float* __restrict__ am)
{
  __shared__ AttnSmem sm;
  const int i0 = blockIdx.x * 32;
  const int b  = blockIdx.y;
  const int n  = blockIdx.z;
  const int tid = threadIdx.x;

  // Stage Qu = q + bias_u, Qv = q + bias_v
  for (int f = tid; f < 512; f += 256) {
    const int ql = f >> 4;
    const int dq = (f & 15) << 2;
    float4 q4 = *(const float4*)(qb + (((size_t)(i0 + ql) * 4 + b) * 512) + n * 64 + dq);
    float4 u4 = *(const float4*)(pbu + n * 64 + dq);
    float4 v4 = *(const float4*)(pbv + n * 64 + dq);
    float4 a = make_float4(q4.x + u4.x, q4.y + u4.y, q4.z + u4.z, q4.w + u4.w);
    float4 c = make_float4(q4.x + v4.x, q4.y + v4.y, q4.z + v4.z, q4.w + v4.w);
    *(float4*)&sm.Qu[ql][dq] = a;
    *(float4*)&sm.Qv[ql][dq] = c;
  }
  if (tid < 128) {
    const int ql = tid >> 2, kk = tid & 3;
    sm.gates[ql][kk] = indice[((size_t)(i0 + ql) * 4 + b) * 4 + kk];
  }
  if (tid < 32) { sm.mrow[tid] = -INFINITY; sm.lrow[tid] = 0.f; }
  __syncthreads();

  const int nt = ((1536 + i0 + 31) >> 6) + 1;   // tiles with any unmasked t
  const int tq = tid >> 5;          // score row group (4 rows)
  const int tt = (tid & 31) << 1;   // score col pair
  const int rq = tid >> 3;          // reduce/prob row
  const int rj = tid & 7;

  // ---------------- pass 1: m, l ----------------
  for (int tile = 0; tile < nt; ++tile) {
    const int tbase = tile << 6;
    const int rbase = tbase + 480 - i0;
    for (int f = tid; f < 1024; f += 256) {
      const int tr = f >> 4, dq = (f & 15) << 2;
      *(float4*)&sm.Ks[tr][dq] =
          *(const float4*)(kvb + ((size_t)(tbase + tr) * 4 + b) * 1024 + n * 64 + dq);
    }
    for (int f = tid; f < 1536; f += 256) {
      const int tr = f >> 4, dq = (f & 15) << 2;
      int rg = rbase + tr;
      rg = rg > 2047 ? 2047 : rg;
      *(float4*)&sm.Rs[tr][dq] =
          *(const float4*)(relb + ((size_t)rg * 4 + b) * 512 + n * 64 + dq);
    }
    __syncthreads();
    attn_scores(sm, i0, tbase, tq, tt);
    __syncthreads();

    float tmax = -INFINITY;
#pragma unroll
    for (int e = 0; e < 8; ++e) tmax = fmaxf(tmax, sm.sb[rq][rj * 8 + e]);
#pragma unroll
    for (int off = 1; off < 8; off <<= 1) tmax = fmaxf(tmax, __shfl_xor(tmax, off));
    const float mold = sm.mrow[rq];
    const float mnew = fmaxf(mold, tmax);
    float ps = 0.f;
#pragma unroll
    for (int e = 0; e < 8; ++e) ps += __expf(sm.sb[rq][rj * 8 + e] - mnew);
#pragma unroll
    for (int off = 1; off < 8; off <<= 1) ps += __shfl_xor(ps, off);
    if (rj == 0) {
      sm.lrow[rq] = sm.lrow[rq] * __expf(mold - mnew) + ps;
      sm.mrow[rq] = mnew;
    }
    __syncthreads();
  }

  // ---------------- pass 2: prob, attn_matrix, PV ----------------
  float acc[8] = {};
  const int q2 = tid >> 3;
  const int dblk = (tid & 7) << 3;

  for (int tile = 0; tile < nt; ++tile) {
    const int tbase = tile << 6;
    const int rbase = tbase + 480 - i0;
    for (int f = tid; f < 1024; f += 256) {
      const int tr = f >> 4, dq = (f & 15) << 2;
      *(float4*)&sm.Ks[tr][dq] =
          *(const float4*)(kvb + ((size_t)(tbase + tr) * 4 + b) * 1024 + n * 64 + dq);
    }
    for (int f = tid; f < 1536; f += 256) {
      const int tr = f >> 4, dq = (f & 15) << 2;
      int rg = rbase + tr;
      rg = rg > 2047 ? 2047 : rg;
      *(float4*)&sm.Rs[tr][dq] =
          *(const float4*)(relb + ((size_t)rg * 4 + b) * 512 + n * 64 + dq);
    }
    __syncthreads();
    attn_scores(sm, i0, tbase, tq, tt);
    __syncthreads();

    {
      const float rl = 1.0f / sm.lrow[rq];
      const float mq = sm.mrow[rq];
#pragma unroll
      for (int e = 0; e < 8; ++e) {
        const float p = __expf(sm.sb[rq][rj * 8 + e] - mq) * rl;
        sm.sb[rq][rj * 8 + e] = p;
        atomicAdd(am + (size_t)(i0 + rq) * 2048 + tbase + rj * 8 + e, p * 0.03125f);
      }
    }
    __syncthreads();
    // V tile into Ks
    for (int f = tid; f < 1024; f += 256) {
      const int tr = f >> 4, dq = (f & 15) << 2;
      *(float4*)&sm.Ks[tr][dq] =
          *(const float4*)(kvb + ((size_t)(tbase + tr) * 4 + b) * 1024 + 512 + n * 64 + dq);
    }
    __syncthreads();
#pragma unroll 8
    for (int tj = 0; tj < 64; ++tj) {
      const float p = sm.sb[q2][tj];
      float4 v0 = *(const float4*)&sm.Ks[tj][dblk];
      float4 v1 = *(const float4*)&sm.Ks[tj][dblk + 4];
      acc[0] += p * v0.x; acc[1] += p * v0.y; acc[2] += p * v0.z; acc[3] += p * v0.w;
      acc[4] += p * v1.x; acc[5] += p * v1.y; acc[6] += p * v1.z; acc[7] += p * v1.w;
    }
    __syncthreads();
  }

  const size_t vo = ((size_t)(i0 + q2) * 4 + b) * 512 + n * 64 + dblk;
  *(float4*)(vecb + vo)     = make_float4(acc[0], acc[1], acc[2], acc[3]);
  *(float4*)(vecb + vo + 4) = make_float4(acc[4], acc[5], acc[6], acc[7]);
}

// ---------------------------------------------------------------------------
// Residual + LayerNorm: out = LN(x + attn_out) * g + b
// One block per row (i*4+b), 256 threads, D=512.
// ---------------------------------------------------------------------------
__global__ __launch_bounds__(256) void ln_f32(
    const float* __restrict__ x, const float* __restrict__ ao,
    const float* __restrict__ g, const float* __restrict__ bb,
    float* __restrict__ out)
{
  const int row = blockIdx.x;
  const int tid = threadIdx.x;
  const size_t base = (size_t)row * 512;
  const float y0 = x[base + tid] + ao[base + tid];
  const float y1 = x[base + 256 + tid] + ao[base + 256 + tid];
  float s  = y0 + y1;
  float ss = y0 * y0 + y1 * y1;
#pragma unroll
  for (int off = 32; off > 0; off >>= 1) {
    s  += __shfl_xor(s, off);
    ss += __shfl_xor(ss, off);
  }
  __shared__ float sred[4], ssred[4], stat[2];
  const int w = tid >> 6;
  if ((tid & 63) == 0) { sred[w] = s; ssred[w] = ss; }
  __syncthreads();
  if (tid == 0) {
    const float S  = sred[0] + sred[1] + sred[2] + sred[3];
    const float SS = ssred[0] + ssred[1] + ssred[2] + ssred[3];
    const float mu = S * (1.f / 512.f);
    const float var = SS * (1.f / 512.f) - mu * mu;
    stat[0] = mu;
    stat[1] = rsqrtf(var + 1e-5f);
  }
  __syncthreads();
  const float mu = stat[0], rs = stat[1];
  out[base + tid]       = (y0 - mu) * rs * g[tid] + bb[tid];
  out[base + 256 + tid] = (y1 - mu) * rs * g[256 + tid] + bb[256 + tid];
}

// ---------------------------------------------------------------------------
// Launch. ws layout (floats):
//   qb   @ 0         : 2048*512   = 1,048,576   (reused for attn_out)
//   kvb  @ 1,048,576 : 8192*1024  = 8,388,608
//   relb @ 9,437,184 : 8192*512   = 4,194,304
//   vecb @ 13,631,488: 2048*512   = 1,048,576
// total 14,680,064 floats = 58.7 MB
// ---------------------------------------------------------------------------
extern "C" void kernel_launch(void* const* d_in, const int* in_sizes, int n_in,
                              void* d_out, int out_size, void* d_ws, size_t ws_size,
                              hipStream_t stream)
{
  (void)in_sizes; (void)n_in; (void)out_size; (void)ws_size;
  const float* x      = (const float*)d_in[0];
  const float* memory = (const float*)d_in[1];
  const float* pos    = (const float*)d_in[2];
  const float* pbu    = (const float*)d_in[3];
  const float* pbv    = (const float*)d_in[4];
  // d_in[5] = mask : recomputed analytically, unused
  const float* indice = (const float*)d_in[6];
  const float* W_q    = (const float*)d_in[7];
  const float* W_kv   = (const float*)d_in[8];
  const float* W_rel  = (const float*)d_in[9];
  const float* W_o    = (const float*)d_in[10];
  const float* ln_g   = (const float*)d_in[11];
  const float* ln_b   = (const float*)d_in[12];

  float* out = (float*)d_out;
  float* am  = out + 1048576;           // attn_matrix [512][2048]

  float* ws   = (float*)d_ws;
  float* qb   = ws;                     // q, later attn_out
  float* kvb  = ws + 1048576;
  float* relb = ws + 9437184;
  float* vecb = ws + 13631488;

  // q = x @ W_q                         [2048 x 512] * [512 x 512]
  gemm_f32<<<dim3(8, 32), 256, 0, stream>>>(x, x, 2048, W_q, qb, 2048, 512, 512);
  // kv = concat(mem, x) @ W_kv          [8192 x 1024]
  gemm_f32<<<dim3(16, 128), 256, 0, stream>>>(memory, x, 6144, W_kv, kvb, 8192, 1024, 512);
  // rel = pos_emb @ W_rel               [8192 x 512]
  gemm_f32<<<dim3(8, 128), 256, 0, stream>>>(pos, pos, 8192, W_rel, relb, 8192, 512, 512);

  hipMemsetAsync(am, 0, (size_t)1048576 * sizeof(float), stream);

  attn_f32<<<dim3(16, 4, 8), 256, 0, stream>>>(qb, kvb, relb, pbu, pbv, indice, vecb, am);

  // attn_out = vec @ W_o  (into qb)
  gemm_f32<<<dim3(8, 32), 256, 0, stream>>>(vecb, vecb, 2048, W_o, qb, 2048, 512, 512);
  // out = LN(x + attn_out)
  ln_f32<<<2048, 256, 0, stream>>>(x, qb, ln_g, ln_b, out);
}

// Round 2
// 409.441 us; speedup vs baseline: 56.4008x; 56.4008x over previous
//
#include <hip/hip_runtime.h>
#include <hip/hip_bf16.h>
#include <math.h>

typedef __bf16 bhalf8 __attribute__((ext_vector_type(8)));
typedef __bf16 bhalf4 __attribute__((ext_vector_type(4)));
typedef float  f32x4  __attribute__((ext_vector_type(4)));

#define MFMA16(a, b, c) __builtin_amdgcn_mfma_f32_16x16x32_bf16(a, b, c, 0, 0, 0)

// ---------------------------------------------------------------------------
// cast f32 -> bf16, n4 float4-groups
// ---------------------------------------------------------------------------
__global__ __launch_bounds__(256) void cast_bf16(const float* __restrict__ in,
                                                 __bf16* __restrict__ out, int n4)
{
  const int i = blockIdx.x * 256 + threadIdx.x;
  if (i < n4) {
    float4 v = ((const float4*)in)[i];
    bhalf4 o;
    o[0] = (__bf16)v.x; o[1] = (__bf16)v.y; o[2] = (__bf16)v.z; o[3] = (__bf16)v.w;
    ((bhalf4*)out)[i] = o;
  }
}

// ---------------------------------------------------------------------------
// transpose+cast: W [K][N] f32 -> Wt [N][K] bf16
// grid (K/64, N/4), block 256
// ---------------------------------------------------------------------------
__global__ __launch_bounds__(256) void transcast(const float* __restrict__ W,
                                                 __bf16* __restrict__ Wt, int K, int N)
{
  const int k = blockIdx.x * 64 + (threadIdx.x & 63);
  const int n = blockIdx.y * 4 + (threadIdx.x >> 6);
  Wt[(size_t)n * K + k] = (__bf16)W[(size_t)k * N + n];
}

// ---------------------------------------------------------------------------
// bf16 MFMA GEMM: C[M][N] = A[M][K] @ Bt[N][K]^T   (Bt is pre-transposed B)
// 128x128 tile, BK=32, 4 waves each computing 64x64.
// Computes D with mfma-M = n-dim (A-operand from Bt) and mfma-N = m-dim
// (B-operand from A), so the C-write is 4-consecutive-n float4/bhalf4 stores.
// ---------------------------------------------------------------------------
template <int OUT_F32>
__global__ __launch_bounds__(256) void gemm_bf16(
    const __bf16* __restrict__ A, const __bf16* __restrict__ Bt,
    void* __restrict__ C, int M, int N, int K)
{
  __shared__ __bf16 a_lds[128][40];
  __shared__ __bf16 b_lds[128][40];
  const int m0 = blockIdx.x * 128;
  const int n0 = blockIdx.y * 128;
  const int tid = threadIdx.x;
  const int w = tid >> 6, l = tid & 63;
  const int wn = (w >> 1) * 64, wm = (w & 1) * 64;
  const int li = l & 15, lq = l >> 4;
  const int lk = lq << 3;

  f32x4 acc[4][4] = {};   // [nsub][msub]

  for (int k0 = 0; k0 < K; k0 += 32) {
    __syncthreads();
#pragma unroll
    for (int c = 0; c < 2; ++c) {
      const int chunk = c * 256 + tid;          // 0..511
      const int row = chunk >> 2, kc = (chunk & 3) << 3;
      *(bhalf8*)&a_lds[row][kc] = *(const bhalf8*)(A + (size_t)(m0 + row) * K + k0 + kc);
      *(bhalf8*)&b_lds[row][kc] = *(const bhalf8*)(Bt + (size_t)(n0 + row) * K + k0 + kc);
    }
    __syncthreads();
    bhalf8 af[4], bf_[4];
#pragma unroll
    for (int s = 0; s < 4; ++s) {
      af[s]  = *(const bhalf8*)&b_lds[wn + s * 16 + li][lk];  // mfma-A: Bt rows (n)
      bf_[s] = *(const bhalf8*)&a_lds[wm + s * 16 + li][lk];  // mfma-B: A rows (m)
    }
#pragma unroll
    for (int ns = 0; ns < 4; ++ns)
#pragma unroll
      for (int ms = 0; ms < 4; ++ms)
        acc[ns][ms] = MFMA16(af[ns], bf_[ms], acc[ns][ms]);
  }

  const int lr = lq << 2;
#pragma unroll
  for (int ms = 0; ms < 4; ++ms) {
    const int m = m0 + wm + ms * 16 + li;
#pragma unroll
    for (int ns = 0; ns < 4; ++ns) {
      const int n = n0 + wn + ns * 16 + lr;
      if (OUT_F32) {
        *(f32x4*)((float*)C + (size_t)m * N + n) = acc[ns][ms];
      } else {
        bhalf4 pk;
#pragma unroll
        for (int r = 0; r < 4; ++r) pk[r] = (__bf16)acc[ns][ms][r];
        *(bhalf4*)((__bf16*)C + (size_t)m * N + n) = pk;
      }
    }
  }
}

// ---------------------------------------------------------------------------
// Fused flash attention, MFMA. Grid (32 i-blocks of 16, 4 b, 8 n), 256 thr.
// S^T[t][i] = K . Qu^T via mfma (lane: col i = l&15, rows t).
// BD on the rel-row grid via mfma -> bd_lds, shift-read bd[tl+15-li][li].
// Online softmax (m,l per i); P -> LDS bf16; PV: out^T = V^T . P^T, wave w
// owns d-range [16w,16w+16). Writes vecb bf16 and (m,l) to ml.
// ---------------------------------------------------------------------------
__global__ __launch_bounds__(256) void attn_mfma(
    const __bf16* __restrict__ qb_, const __bf16* __restrict__ kvb,
    const __bf16* __restrict__ relb, const float* __restrict__ pbu,
    const float* __restrict__ pbv, const float* __restrict__ indice,
    __bf16* __restrict__ vecb, float* __restrict__ ml)
{
  __shared__ __bf16 K_l[128][72];
  __shared__ __bf16 R_l[160][72];
  __shared__ __bf16 Vt[64][136];
  __shared__ __bf16 Qu[16][72];
  __shared__ __bf16 Qv[16][72];
  __shared__ __bf16 P_l[16][136];
  __shared__ float  bd[144][18];
  __shared__ float  red[2][4][16];

  const int i0 = blockIdx.x * 16;
  const int b  = blockIdx.y;
  const int n  = blockIdx.z;
  const int tid = threadIdx.x;
  const int w  = tid >> 6;
  const int l  = tid & 63;
  const int li = l & 15;
  const int lq = l >> 4;

  if (tid < 128) {
    const int row = tid >> 3, dc = (tid & 7) << 3;
    bhalf8 q8 = *(const bhalf8*)(qb_ + ((size_t)(i0 + row) * 4 + b) * 512 + n * 64 + dc);
    float ub[8], vb[8];
    *(float4*)&ub[0] = *(const float4*)(pbu + n * 64 + dc);
    *(float4*)&ub[4] = *(const float4*)(pbu + n * 64 + dc + 4);
    *(float4*)&vb[0] = *(const float4*)(pbv + n * 64 + dc);
    *(float4*)&vb[4] = *(const float4*)(pbv + n * 64 + dc + 4);
    bhalf8 qu, qv;
#pragma unroll
    for (int j = 0; j < 8; ++j) {
      const float qf = (float)q8[j];
      qu[j] = (__bf16)(qf + ub[j]);
      qv[j] = (__bf16)(qf + vb[j]);
    }
    *(bhalf8*)&Qu[row][dc] = qu;
    *(bhalf8*)&Qv[row][dc] = qv;
  }
  float g0, g1, g2, g3;
  {
    const float* gp = indice + ((size_t)(i0 + li) * 4 + b) * 4;
    g0 = gp[0]; g1 = gp[1]; g2 = gp[2]; g3 = gp[3];
  }
  float m_run = -1e30f, l_run = 0.f;
  f32x4 oacc = {0.f, 0.f, 0.f, 0.f};
  const int nt = ((1536 + i0 + 15) >> 7) + 1;

  for (int tile = 0; tile < nt; ++tile) {
    const int tb = tile << 7;
    const int rb = tb + 496 - i0;
    __syncthreads();                       // protect prior-tile LDS reads
    // stage K and V (transposed)
#pragma unroll
    for (int c = 0; c < 4; ++c) {
      const int chunk = c * 256 + tid;     // 0..1023
      const int row = chunk >> 3, dc = (chunk & 7) << 3;
      const __bf16* kp = kvb + ((size_t)(tb + row) * 4 + b) * 1024 + n * 64 + dc;
      *(bhalf8*)&K_l[row][dc] = *(const bhalf8*)kp;
      bhalf8 v8 = *(const bhalf8*)(kp + 512);
#pragma unroll
      for (int j = 0; j < 8; ++j) Vt[dc + j][row] = v8[j];
    }
    // stage R (160 rows, clamped)
#pragma unroll
    for (int c = 0; c < 5; ++c) {
      const int chunk = c * 256 + tid;     // 0..1279
      const int row = chunk >> 3, dc = (chunk & 7) << 3;
      int rg = rb + row; rg = rg > 2047 ? 2047 : rg;
      *(bhalf8*)&R_l[row][dc] =
          *(const bhalf8*)(relb + ((size_t)rg * 4 + b) * 512 + n * 64 + dc);
    }
    __syncthreads();
    // BD mfmas: wave w handles r-subtiles {w, w+4, w+8}
#pragma unroll
    for (int rr = 0; rr < 3; ++rr) {
      const int rs = w + rr * 4;
      if (rs < 9) {
        f32x4 c0 = {0.f, 0.f, 0.f, 0.f};
        c0 = MFMA16(*(const bhalf8*)&R_l[rs * 16 + li][lq * 8],
                    *(const bhalf8*)&Qv[li][lq * 8], c0);
        c0 = MFMA16(*(const bhalf8*)&R_l[rs * 16 + li][32 + lq * 8],
                    *(const bhalf8*)&Qv[li][32 + lq * 8], c0);
#pragma unroll
        for (int r = 0; r < 4; ++r) bd[rs * 16 + lq * 4 + r][li] = c0[r];
      }
    }
    // AC mfmas: wave w covers t_local [32w, 32w+32)
    f32x4 s0 = {0.f, 0.f, 0.f, 0.f}, s1 = {0.f, 0.f, 0.f, 0.f};
    {
      bhalf8 bq0 = *(const bhalf8*)&Qu[li][lq * 8];
      bhalf8 bq1 = *(const bhalf8*)&Qu[li][32 + lq * 8];
      s0 = MFMA16(*(const bhalf8*)&K_l[w * 32 + li][lq * 8], bq0, s0);
      s0 = MFMA16(*(const bhalf8*)&K_l[w * 32 + li][32 + lq * 8], bq1, s0);
      s1 = MFMA16(*(const bhalf8*)&K_l[w * 32 + 16 + li][lq * 8], bq0, s1);
      s1 = MFMA16(*(const bhalf8*)&K_l[w * 32 + 16 + li][32 + lq * 8], bq1, s1);
    }
    __syncthreads();                       // bd visible
    // assemble scores; per-lane i = i0+li
    float sv[8];
    float mymax = -1e30f;
#pragma unroll
    for (int ts = 0; ts < 2; ++ts) {
#pragma unroll
      for (int r = 0; r < 4; ++r) {
        const int tl = w * 32 + ts * 16 + lq * 4 + r;
        const int t  = tb + tl;
        float s = -1e30f;
        if (t <= 1536 + i0 + li) {
          const float ac  = ts ? s1[r] : s0[r];
          const float bdv = bd[tl + 15 - li][li];
          const int tk = t >> 9;
          const float ga = tk == 0 ? g0 : (tk == 1 ? g1 : (tk == 2 ? g2 : g3));
          const int rk = (t + 511 - i0 - li) >> 9;
          const float gb = rk == 0 ? g0 : (rk == 1 ? g1 : (rk == 2 ? g2 : g3));
          s = (ac * ga + bdv * gb) * 0.125f;
        }
        sv[ts * 4 + r] = s;
        mymax = fmaxf(mymax, s);
      }
    }
    mymax = fmaxf(mymax, __shfl_xor(mymax, 16));
    mymax = fmaxf(mymax, __shfl_xor(mymax, 32));
    if (l < 16) red[0][w][li] = mymax;
    __syncthreads();
    const float mt = fmaxf(fmaxf(red[0][0][li], red[0][1][li]),
                           fmaxf(red[0][2][li], red[0][3][li]));
    const float mnew = fmaxf(m_run, mt);
    const float scl = __expf(m_run - mnew);
    float psum = 0.f;
    float pf[8];
#pragma unroll
    for (int e = 0; e < 8; ++e) {
      const float p = __expf(sv[e] - mnew);
      pf[e] = p; psum += p;
    }
    psum += __shfl_xor(psum, 16);
    psum += __shfl_xor(psum, 32);
    if (l < 16) red[1][w][li] = psum;
#pragma unroll
    for (int ts = 0; ts < 2; ++ts) {
      bhalf4 pk;
#pragma unroll
      for (int r = 0; r < 4; ++r) pk[r] = (__bf16)pf[ts * 4 + r];
      *(bhalf4*)&P_l[li][w * 32 + ts * 16 + lq * 4] = pk;
    }
    __syncthreads();                       // red[1] + P_l visible
    const float lsum = red[1][0][li] + red[1][1][li] + red[1][2][li] + red[1][3][li];
    l_run = l_run * scl + lsum;
    m_run = mnew;
    oacc *= scl;
#pragma unroll
    for (int kt = 0; kt < 4; ++kt) {
      oacc = MFMA16(*(const bhalf8*)&Vt[w * 16 + li][kt * 32 + lq * 8],
                    *(const bhalf8*)&P_l[li][kt * 32 + lq * 8], oacc);
    }
  }
  const float rli = 1.f / l_run;
  bhalf4 ov;
#pragma unroll
  for (int r = 0; r < 4; ++r) ov[r] = (__bf16)(oacc[r] * rli);
  *(bhalf4*)(vecb + ((size_t)(i0 + li) * 4 + b) * 512 + n * 64 + w * 16 + lq * 4) = ov;
  if (w == 0 && l < 16) {
    float* mp = ml + ((size_t)(b * 8 + n) * 512 + i0 + li) * 2;
    mp[0] = m_run; mp[1] = l_run;
  }
}

// ---------------------------------------------------------------------------
// attn_matrix recompute kernel: grid (16 t-tiles, 32 i-blocks), 256 thr.
// Loops 32 (b,n) planes, recomputes S via same MFMA path, accumulates
// mean prob into registers, writes am exactly once (masked -> 0).
// ---------------------------------------------------------------------------
__global__ __launch_bounds__(256) void am_mfma(
    const __bf16* __restrict__ qb_, const __bf16* __restrict__ kvb,
    const __bf16* __restrict__ relb, const float* __restrict__ pbu,
    const float* __restrict__ pbv, const float* __restrict__ indice,
    const float* __restrict__ ml, float* __restrict__ am)
{
  __shared__ __bf16 K_l[128][72];
  __shared__ __bf16 R_l[160][72];
  __shared__ __bf16 Qu[16][72];
  __shared__ __bf16 Qv[16][72];
  __shared__ float  bd[144][18];
  __shared__ float  mlL[16][2];

  const int tb = blockIdx.x * 128;
  const int i0 = blockIdx.y * 16;
  const int tid = threadIdx.x;
  const int w  = tid >> 6;
  const int l  = tid & 63;
  const int li = l & 15;
  const int lq = l >> 4;
  f32x4 acc0 = {0.f, 0.f, 0.f, 0.f}, acc1 = {0.f, 0.f, 0.f, 0.f};

  if (tb <= 1536 + i0 + 15) {
    const int rb = tb + 496 - i0;
    for (int bn = 0; bn < 32; ++bn) {
      const int bb = bn >> 3, nn = bn & 7;
      __syncthreads();
      if (tid < 128) {
        const int row = tid >> 3, dc = (tid & 7) << 3;
        bhalf8 q8 = *(const bhalf8*)(qb_ + ((size_t)(i0 + row) * 4 + bb) * 512 + nn * 64 + dc);
        float ub[8], vb[8];
        *(float4*)&ub[0] = *(const float4*)(pbu + nn * 64 + dc);
        *(float4*)&ub[4] = *(const float4*)(pbu + nn * 64 + dc + 4);
        *(float4*)&vb[0] = *(const float4*)(pbv + nn * 64 + dc);
        *(float4*)&vb[4] = *(const float4*)(pbv + nn * 64 + dc + 4);
        bhalf8 qu, qv;
#pragma unroll
        for (int j = 0; j < 8; ++j) {
          const float qf = (float)q8[j];
          qu[j] = (__bf16)(qf + ub[j]);
          qv[j] = (__bf16)(qf + vb[j]);
        }
        *(bhalf8*)&Qu[row][dc] = qu;
        *(bhalf8*)&Qv[row][dc] = qv;
      }
      if (tid < 32) mlL[tid >> 1][tid & 1] = ml[((size_t)bn * 512 + i0 + (tid >> 1)) * 2 + (tid & 1)];
#pragma unroll
      for (int c = 0; c < 4; ++c) {
        const int chunk = c * 256 + tid;
        const int row = chunk >> 3, dc = (chunk & 7) << 3;
        *(bhalf8*)&K_l[row][dc] =
            *(const bhalf8*)(kvb + ((size_t)(tb + row) * 4 + bb) * 1024 + nn * 64 + dc);
      }
#pragma unroll
      for (int c = 0; c < 5; ++c) {
        const int chunk = c * 256 + tid;
        const int row = chunk >> 3, dc = (chunk & 7) << 3;
        int rg = rb + row; rg = rg > 2047 ? 2047 : rg;
        *(bhalf8*)&R_l[row][dc] =
            *(const bhalf8*)(relb + ((size_t)rg * 4 + bb) * 512 + nn * 64 + dc);
      }
      const float* gp = indice + ((size_t)(i0 + li) * 4 + bb) * 4;
      const float g0 = gp[0], g1 = gp[1], g2 = gp[2], g3 = gp[3];
      __syncthreads();
#pragma unroll
      for (int rr = 0; rr < 3; ++rr) {
        const int rs = w + rr * 4;
        if (rs < 9) {
          f32x4 c0 = {0.f, 0.f, 0.f, 0.f};
          c0 = MFMA16(*(const bhalf8*)&R_l[rs * 16 + li][lq * 8],
                      *(const bhalf8*)&Qv[li][lq * 8], c0);
          c0 = MFMA16(*(const bhalf8*)&R_l[rs * 16 + li][32 + lq * 8],
                      *(const bhalf8*)&Qv[li][32 + lq * 8], c0);
#pragma unroll
          for (int r = 0; r < 4; ++r) bd[rs * 16 + lq * 4 + r][li] = c0[r];
        }
      }
      // AC for t-subtiles w and w+4
      f32x4 s0 = {0.f, 0.f, 0.f, 0.f}, s1 = {0.f, 0.f, 0.f, 0.f};
      {
        bhalf8 bq0 = *(const bhalf8*)&Qu[li][lq * 8];
        bhalf8 bq1 = *(const bhalf8*)&Qu[li][32 + lq * 8];
        s0 = MFMA16(*(const bhalf8*)&K_l[w * 16 + li][lq * 8], bq0, s0);
        s0 = MFMA16(*(const bhalf8*)&K_l[w * 16 + li][32 + lq * 8], bq1, s0);
        s1 = MFMA16(*(const bhalf8*)&K_l[(w + 4) * 16 + li][lq * 8], bq0, s1);
        s1 = MFMA16(*(const bhalf8*)&K_l[(w + 4) * 16 + li][32 + lq * 8], bq1, s1);
      }
      __syncthreads();
      const float mrow = mlL[li][0];
      const float rli  = 1.f / mlL[li][1];
#pragma unroll
      for (int q = 0; q < 2; ++q) {
#pragma unroll
        for (int r = 0; r < 4; ++r) {
          const int tl = (q ? (w + 4) : w) * 16 + lq * 4 + r;
          const int t = tb + tl;
          if (t <= 1536 + i0 + li) {
            const float ac  = q ? s1[r] : s0[r];
            const float bdv = bd[tl + 15 - li][li];
            const int tk = t >> 9;
            const float ga = tk == 0 ? g0 : (tk == 1 ? g1 : (tk == 2 ? g2 : g3));
            const int rk = (t + 511 - i0 - li) >> 9;
            const float gb = rk == 0 ? g0 : (rk == 1 ? g1 : (rk == 2 ? g2 : g3));
            const float s = (ac * ga + bdv * gb) * 0.125f;
            const float p = __expf(s - mrow) * rli;
            if (q) acc1[r] += p; else acc0[r] += p;
          }
        }
      }
    }
  }
  const float sc = 1.f / 32.f;
  f32x4 o0 = acc0 * sc, o1 = acc1 * sc;
  float* ap = am + (size_t)(i0 + li) * 2048 + tb;
  *(f32x4*)(ap + w * 16 + lq * 4) = o0;
  *(f32x4*)(ap + (w + 4) * 16 + lq * 4) = o1;
}

// ---------------------------------------------------------------------------
// Residual + LayerNorm
// ---------------------------------------------------------------------------
__global__ __launch_bounds__(256) void ln_f32(
    const float* __restrict__ x, const float* __restrict__ ao,
    const float* __restrict__ g, const float* __restrict__ bb,
    float* __restrict__ out)
{
  const int row = blockIdx.x;
  const int tid = threadIdx.x;
  const size_t base = (size_t)row * 512;
  const float y0 = x[base + tid] + ao[base + tid];
  const float y1 = x[base + 256 + tid] + ao[base + 256 + tid];
  float s  = y0 + y1;
  float ss = y0 * y0 + y1 * y1;
#pragma unroll
  for (int off = 32; off > 0; off >>= 1) {
    s  += __shfl_xor(s, off);
    ss += __shfl_xor(ss, off);
  }
  __shared__ float sred[4], ssred[4], stat[2];
  const int w = tid >> 6;
  if ((tid & 63) == 0) { sred[w] = s; ssred[w] = ss; }
  __syncthreads();
  if (tid == 0) {
    const float S  = sred[0] + sred[1] + sred[2] + sred[3];
    const float SS = ssred[0] + ssred[1] + ssred[2] + ssred[3];
    const float mu = S * (1.f / 512.f);
    const float var = SS * (1.f / 512.f) - mu * mu;
    stat[0] = mu;
    stat[1] = rsqrtf(var + 1e-5f);
  }
  __syncthreads();
  const float mu = stat[0], rs = stat[1];
  out[base + tid]       = (y0 - mu) * rs * g[tid] + bb[tid];
  out[base + 256 + tid] = (y1 - mu) * rs * g[256 + tid] + bb[256 + tid];
}

// ---------------------------------------------------------------------------
// Launch. ws layout (bf16 elems unless noted):
//   cb    @ 0          4,194,304   (concat(mem,x) bf16, rows t*4+b)
//   posb  @ 4,194,304  4,194,304
//   qb    @ 8,388,608  1,048,576
//   kvb   @ 9,437,184  8,388,608
//   relb  @ 17,825,792 4,194,304
//   vecb  @ 22,020,096 1,048,576
//   wqt   @ 23,068,672 262,144
//   wkvt  @ 23,330,816 524,288
//   wrelt @ 23,855,104 262,144
//   wot   @ 24,117,248 262,144
//   aof (f32) / ml (f32) after -> total ~50.8 MB
// ---------------------------------------------------------------------------
extern "C" void kernel_launch(void* const* d_in, const int* in_sizes, int n_in,
                              void* d_out, int out_size, void* d_ws, size_t ws_size,
                              hipStream_t stream)
{
  (void)in_sizes; (void)n_in; (void)out_size; (void)ws_size;
  const float* x      = (const float*)d_in[0];
  const float* memory = (const float*)d_in[1];
  const float* pos    = (const float*)d_in[2];
  const float* pbu    = (const float*)d_in[3];
  const float* pbv    = (const float*)d_in[4];
  const float* indice = (const float*)d_in[6];
  const float* W_q    = (const float*)d_in[7];
  const float* W_kv   = (const float*)d_in[8];
  const float* W_rel  = (const float*)d_in[9];
  const float* W_o    = (const float*)d_in[10];
  const float* ln_g   = (const float*)d_in[11];
  const float* ln_b   = (const float*)d_in[12];

  float* out = (float*)d_out;
  float* am  = out + 1048576;

  __bf16* cb    = (__bf16*)d_ws;
  __bf16* posb  = cb + 4194304;
  __bf16* qb    = posb + 4194304;
  __bf16* kvb   = qb + 1048576;
  __bf16* relb  = kvb + 8388608;
  __bf16* vecb  = relb + 4194304;
  __bf16* wqt   = vecb + 1048576;
  __bf16* wkvt  = wqt + 262144;
  __bf16* wrelt = wkvt + 524288;
  __bf16* wot   = wrelt + 262144;
  float*  aof   = (float*)(wot + 262144);
  float*  ml    = aof + 1048576;
  __bf16* xb    = cb + 3145728;   // x rows start at row 6144

  cast_bf16<<<3072, 256, 0, stream>>>(memory, cb, 786432);
  cast_bf16<<<1024, 256, 0, stream>>>(x, xb, 262144);
  cast_bf16<<<4096, 256, 0, stream>>>(pos, posb, 1048576);
  transcast<<<dim3(8, 128), 256, 0, stream>>>(W_q,   wqt,   512, 512);
  transcast<<<dim3(8, 256), 256, 0, stream>>>(W_kv,  wkvt,  512, 1024);
  transcast<<<dim3(8, 128), 256, 0, stream>>>(W_rel, wrelt, 512, 512);
  transcast<<<dim3(8, 128), 256, 0, stream>>>(W_o,   wot,   512, 512);

  gemm_bf16<0><<<dim3(16, 4), 256, 0, stream>>>(xb,   wqt,  qb,  2048, 512, 512);
  gemm_bf16<0><<<dim3(64, 8), 256, 0, stream>>>(cb,   wkvt, kvb, 8192, 1024, 512);
  gemm_bf16<0><<<dim3(64, 4), 256, 0, stream>>>(posb, wrelt, relb, 8192, 512, 512);

  attn_mfma<<<dim3(32, 4, 8), 256, 0, stream>>>(qb, kvb, relb, pbu, pbv, indice, vecb, ml);
  am_mfma<<<dim3(16, 32), 256, 0, stream>>>(qb, kvb, relb, pbu, pbv, indice, ml, am);

  gemm_bf16<1><<<dim3(16, 4), 256, 0, stream>>>(vecb, wot, aof, 2048, 512, 512);
  ln_f32<<<2048, 256, 0, stream>>>(x, aof, ln_g, ln_b, out);
}

// Round 3
// 369.787 us; speedup vs baseline: 62.4490x; 1.1072x over previous
//
#include <hip/hip_runtime.h>
#include <hip/hip_bf16.h>
#include <math.h>

typedef __bf16 bhalf8 __attribute__((ext_vector_type(8)));
typedef __bf16 bhalf4 __attribute__((ext_vector_type(4)));
typedef float  f32x4  __attribute__((ext_vector_type(4)));

#define MFMA16(a, b, c) __builtin_amdgcn_mfma_f32_16x16x32_bf16(a, b, c, 0, 0, 0)

// ---------------------------------------------------------------------------
// cast f32 -> bf16
// ---------------------------------------------------------------------------
__global__ __launch_bounds__(256) void cast_bf16(const float* __restrict__ in,
                                                 __bf16* __restrict__ out, int n4)
{
  const int i = blockIdx.x * 256 + threadIdx.x;
  if (i < n4) {
    float4 v = ((const float4*)in)[i];
    bhalf4 o;
    o[0] = (__bf16)v.x; o[1] = (__bf16)v.y; o[2] = (__bf16)v.z; o[3] = (__bf16)v.w;
    ((bhalf4*)out)[i] = o;
  }
}

// ---------------------------------------------------------------------------
// transpose+cast: W [K][N] f32 -> Wt [N][K] bf16
// ---------------------------------------------------------------------------
__global__ __launch_bounds__(256) void transcast(const float* __restrict__ W,
                                                 __bf16* __restrict__ Wt, int K, int N)
{
  const int k = blockIdx.x * 64 + (threadIdx.x & 63);
  const int n = blockIdx.y * 4 + (threadIdx.x >> 6);
  Wt[(size_t)n * K + k] = (__bf16)W[(size_t)k * N + n];
}

// ---------------------------------------------------------------------------
// bf16 MFMA GEMM (unchanged from round 2): C[M][N] = A[M][K] @ Bt[N][K]^T
// ---------------------------------------------------------------------------
template <int OUT_F32>
__global__ __launch_bounds__(256) void gemm_bf16(
    const __bf16* __restrict__ A, const __bf16* __restrict__ Bt,
    void* __restrict__ C, int M, int N, int K)
{
  __shared__ __bf16 a_lds[128][40];
  __shared__ __bf16 b_lds[128][40];
  const int m0 = blockIdx.x * 128;
  const int n0 = blockIdx.y * 128;
  const int tid = threadIdx.x;
  const int w = tid >> 6, l = tid & 63;
  const int wn = (w >> 1) * 64, wm = (w & 1) * 64;
  const int li = l & 15, lq = l >> 4;
  const int lk = lq << 3;

  f32x4 acc[4][4] = {};

  for (int k0 = 0; k0 < K; k0 += 32) {
    __syncthreads();
#pragma unroll
    for (int c = 0; c < 2; ++c) {
      const int chunk = c * 256 + tid;
      const int row = chunk >> 2, kc = (chunk & 3) << 3;
      *(bhalf8*)&a_lds[row][kc] = *(const bhalf8*)(A + (size_t)(m0 + row) * K + k0 + kc);
      *(bhalf8*)&b_lds[row][kc] = *(const bhalf8*)(Bt + (size_t)(n0 + row) * K + k0 + kc);
    }
    __syncthreads();
    bhalf8 af[4], bf_[4];
#pragma unroll
    for (int s = 0; s < 4; ++s) {
      af[s]  = *(const bhalf8*)&b_lds[wn + s * 16 + li][lk];
      bf_[s] = *(const bhalf8*)&a_lds[wm + s * 16 + li][lk];
    }
#pragma unroll
    for (int ns = 0; ns < 4; ++ns)
#pragma unroll
      for (int ms = 0; ms < 4; ++ms)
        acc[ns][ms] = MFMA16(af[ns], bf_[ms], acc[ns][ms]);
  }

  const int lr = lq << 2;
#pragma unroll
  for (int ms = 0; ms < 4; ++ms) {
    const int m = m0 + wm + ms * 16 + li;
#pragma unroll
    for (int ns = 0; ns < 4; ++ns) {
      const int n = n0 + wn + ns * 16 + lr;
      if (OUT_F32) {
        *(f32x4*)((float*)C + (size_t)m * N + n) = acc[ns][ms];
      } else {
        bhalf4 pk;
#pragma unroll
        for (int r = 0; r < 4; ++r) pk[r] = (__bf16)acc[ns][ms][r];
        *(bhalf4*)((__bf16*)C + (size_t)m * N + n) = pk;
      }
    }
  }
}

// ---------------------------------------------------------------------------
// V transpose: vtb[plane][d][t] <- kvb V-half [t][plane-slice d]
// grid (32 t-tiles of 64, 32 planes), 256 thr.
// ---------------------------------------------------------------------------
__global__ __launch_bounds__(256) void vtrans(const __bf16* __restrict__ kvb,
                                              __bf16* __restrict__ vtb)
{
  __shared__ __bf16 T2[64][72];   // [d][t_local]
  const int t0 = blockIdx.x * 64;
  const int p = blockIdx.y;
  const int b = p >> 3, n = p & 7;
  const int tid = threadIdx.x;
#pragma unroll
  for (int c = 0; c < 2; ++c) {
    const int e = c * 256 + tid;             // 512 chunks
    const int tl = e >> 3, d8 = (e & 7) << 3;
    bhalf8 v8 = *(const bhalf8*)(kvb + ((size_t)(t0 + tl) * 4 + b) * 1024 + 512 + n * 64 + d8);
#pragma unroll
    for (int j = 0; j < 8; ++j) T2[d8 + j][tl] = v8[j];
  }
  __syncthreads();
#pragma unroll
  for (int c = 0; c < 2; ++c) {
    const int e = c * 256 + tid;
    const int d = e >> 3, t8 = (e & 7) << 3;
    bhalf8 v = *(const bhalf8*)&T2[d][t8];
    *(bhalf8*)(vtb + ((size_t)p * 64 + d) * 2048 + t0 + t8) = v;
  }
}

// ---------------------------------------------------------------------------
// Fused flash attention v3: no tile staging; K/R/V^T fragments straight from
// L2-resident global. QB=32, 512 threads (8 waves), grid 512 (swizzled).
// Wave w: t-subtile w for AC/BD (both i-tiles); (dg=w>>1, it=w&1) for PV.
// ---------------------------------------------------------------------------
__global__ __launch_bounds__(512, 4) void attn_v3(
    const __bf16* __restrict__ qb_, const __bf16* __restrict__ kvb,
    const __bf16* __restrict__ relb, const __bf16* __restrict__ vtb,
    const float* __restrict__ pbu, const float* __restrict__ pbv,
    const float* __restrict__ indice,
    __bf16* __restrict__ vecb, float* __restrict__ ml)
{
  __shared__ __align__(16) __bf16 P_l[32][136];
  __shared__ __align__(16) __bf16 bdl[160][33];
  __shared__ float red0[8][33];
  __shared__ float red1[8][33];
  __shared__ float lfin[32];

  const int bid = blockIdx.x;
  const int wrk = ((bid & 7) << 6) + (bid >> 3);   // XCD-contig planes
  const int plane = wrk >> 4;
  const int i0 = (wrk & 15) << 5;
  const int b = plane >> 3, n = plane & 7;
  const int tid = threadIdx.x;
  const int w = tid >> 6;
  const int l = tid & 63;
  const int li = l & 15;
  const int lq = l >> 4;

  const __bf16* kbase = kvb + (size_t)b * 1024 + n * 64;
  const __bf16* rbase = relb + (size_t)b * 512 + n * 64;
  const __bf16* vbase = vtb + (size_t)plane * 131072;

  // per-lane Q fragments + gates for both i-tiles
  bhalf8 qu[2][2], qv[2][2];
  float g[2][4];
#pragma unroll
  for (int it = 0; it < 2; ++it) {
    const int i = i0 + it * 16 + li;
    const float* gp = indice + ((size_t)i * 4 + b) * 4;
    g[it][0] = gp[0]; g[it][1] = gp[1]; g[it][2] = gp[2]; g[it][3] = gp[3];
#pragma unroll
    for (int h = 0; h < 2; ++h) {
      const int dc = h * 32 + lq * 8;
      bhalf8 q8 = *(const bhalf8*)(qb_ + ((size_t)i * 4 + b) * 512 + n * 64 + dc);
      float ub[8], vb[8];
      *(float4*)&ub[0] = *(const float4*)(pbu + n * 64 + dc);
      *(float4*)&ub[4] = *(const float4*)(pbu + n * 64 + dc + 4);
      *(float4*)&vb[0] = *(const float4*)(pbv + n * 64 + dc);
      *(float4*)&vb[4] = *(const float4*)(pbv + n * 64 + dc + 4);
      bhalf8 a, c;
#pragma unroll
      for (int j = 0; j < 8; ++j) {
        const float qf = (float)q8[j];
        a[j] = (__bf16)(qf + ub[j]);
        c[j] = (__bf16)(qf + vb[j]);
      }
      qu[it][h] = a; qv[it][h] = c;
    }
  }

  float m0 = -1e30f, m1 = -1e30f, l0 = 0.f, l1 = 0.f;
  f32x4 oacc = {0.f, 0.f, 0.f, 0.f};
  const int dgw = w >> 1, itw = w & 1;
  const int nt = ((1536 + i0 + 31) >> 7) + 1;

  for (int tile = 0; tile < nt; ++tile) {
    const int tb = tile << 7;
    const int rb = tb + 480 - i0;

    // ---- BD: rel fragments from global, gated bf16 into bdl ----
#pragma unroll
    for (int ri = 0; ri < 2; ++ri) {
      const int rs = w + ri * 8;
      if (ri == 0 || rs < 10) {
        int row = rb + rs * 16 + li;
        row = row > 2047 ? 2047 : row;
        const __bf16* rp = rbase + (size_t)row * 2048;
        bhalf8 a0 = *(const bhalf8*)(rp + lq * 8);
        bhalf8 a1 = *(const bhalf8*)(rp + 32 + lq * 8);
#pragma unroll
        for (int it = 0; it < 2; ++it) {
          f32x4 c = {0.f, 0.f, 0.f, 0.f};
          c = MFMA16(a0, qv[it][0], c);
          c = MFMA16(a1, qv[it][1], c);
#pragma unroll
          for (int r = 0; r < 4; ++r) {
            const int rowl = rs * 16 + lq * 4 + r;
            int rk = (rb + rowl) >> 9; rk = rk > 3 ? 3 : rk;
            bdl[rowl][it * 16 + li] = (__bf16)(c[r] * g[it][rk]);
          }
        }
      }
    }
    // ---- AC ----
    f32x4 s[2];
    {
      const __bf16* kp = kbase + (size_t)(tb + w * 16 + li) * 4096;
      bhalf8 a0 = *(const bhalf8*)(kp + lq * 8);
      bhalf8 a1 = *(const bhalf8*)(kp + 32 + lq * 8);
#pragma unroll
      for (int it = 0; it < 2; ++it) {
        f32x4 c = {0.f, 0.f, 0.f, 0.f};
        c = MFMA16(a0, qu[it][0], c);
        c = MFMA16(a1, qu[it][1], c);
        s[it] = c;
      }
    }
    __syncthreads();   // bd visible

    // ---- scores ----
    float sv[2][4];
    float tmax[2] = {-1e30f, -1e30f};
#pragma unroll
    for (int it = 0; it < 2; ++it) {
      const int i = i0 + it * 16 + li;
#pragma unroll
      for (int r = 0; r < 4; ++r) {
        const int tl = w * 16 + lq * 4 + r;
        const int t = tb + tl;
        float sc = -1e30f;
        if (t <= 1536 + i) {
          const float bdv = (float)bdl[tl + 31 - it * 16 - li][it * 16 + li];
          sc = (s[it][r] * g[it][t >> 9] + bdv) * 0.125f;
        }
        sv[it][r] = sc;
        tmax[it] = fmaxf(tmax[it], sc);
      }
    }
    tmax[0] = fmaxf(tmax[0], __shfl_xor(tmax[0], 16));
    tmax[0] = fmaxf(tmax[0], __shfl_xor(tmax[0], 32));
    tmax[1] = fmaxf(tmax[1], __shfl_xor(tmax[1], 16));
    tmax[1] = fmaxf(tmax[1], __shfl_xor(tmax[1], 32));
    if (l < 16) { red0[w][li] = tmax[0]; red0[w][16 + li] = tmax[1]; }
    __syncthreads();

    float mn[2], scl[2];
#pragma unroll
    for (int it = 0; it < 2; ++it) {
      const int ic = it * 16 + li;
      float mt = red0[0][ic];
#pragma unroll
      for (int ww = 1; ww < 8; ++ww) mt = fmaxf(mt, red0[ww][ic]);
      const float mo = it ? m1 : m0;
      mn[it] = fmaxf(mo, mt);
      scl[it] = __expf(mo - mn[it]);
    }
    float ps[2] = {0.f, 0.f};
#pragma unroll
    for (int it = 0; it < 2; ++it) {
      bhalf4 pk;
#pragma unroll
      for (int r = 0; r < 4; ++r) {
        const float p = __expf(sv[it][r] - mn[it]);
        ps[it] += p;
        pk[r] = (__bf16)p;
      }
      *(bhalf4*)&P_l[it * 16 + li][w * 16 + lq * 4] = pk;
    }
    ps[0] += __shfl_xor(ps[0], 16); ps[0] += __shfl_xor(ps[0], 32);
    ps[1] += __shfl_xor(ps[1], 16); ps[1] += __shfl_xor(ps[1], 32);
    if (l < 16) { red1[w][li] = ps[0]; red1[w][16 + li] = ps[1]; }
    __syncthreads();   // red1 + P_l visible

    {
      float ls0 = 0.f, ls1 = 0.f;
#pragma unroll
      for (int ww = 0; ww < 8; ++ww) { ls0 += red1[ww][li]; ls1 += red1[ww][16 + li]; }
      l0 = l0 * scl[0] + ls0; m0 = mn[0];
      l1 = l1 * scl[1] + ls1; m1 = mn[1];
    }
    // ---- PV ----
    oacc *= scl[itw];
    {
      const __bf16* vp = vbase + (size_t)(dgw * 16 + li) * 2048 + tb;
#pragma unroll
      for (int kt = 0; kt < 4; ++kt) {
        bhalf8 af = *(const bhalf8*)(vp + kt * 32 + lq * 8);
        bhalf8 bf_ = *(const bhalf8*)&P_l[itw * 16 + li][kt * 32 + lq * 8];
        oacc = MFMA16(af, bf_, oacc);
      }
    }
  }

  // ---- epilogue: cross-wave assembly via LDS, coalesced store ----
  __syncthreads();
  float* obuf = (float*)&P_l[0][0];   // 32x68 f32 fits in P_l (8704 B)
  if (w == 0 && l < 16) {
    lfin[li] = 1.f / l0;
    lfin[16 + li] = 1.f / l1;
    float* mp0 = ml + ((size_t)plane * 512 + i0 + li) * 2;
    mp0[0] = m0; mp0[1] = l0;
    float* mp1 = ml + ((size_t)plane * 512 + i0 + 16 + li) * 2;
    mp1[0] = m1; mp1[1] = l1;
  }
#pragma unroll
  for (int r = 0; r < 4; ++r)
    obuf[(itw * 16 + li) * 68 + dgw * 16 + lq * 4 + r] = oacc[r];
  __syncthreads();
  {
    const int iloc = tid >> 4, dq = tid & 15;
    const float rli = lfin[iloc];
    f32x4 o = *(f32x4*)&obuf[iloc * 68 + dq * 4];
    bhalf4 ov;
#pragma unroll
    for (int r = 0; r < 4; ++r) ov[r] = (__bf16)(o[r] * rli);
    *(bhalf4*)(vecb + ((size_t)(i0 + iloc) * 4 + b) * 512 + n * 64 + dq * 4) = ov;
  }
}

// ---------------------------------------------------------------------------
// attn_matrix recompute: grid 1024 (swizzled) = (16 tb, 16 i0, 4 b), 512 thr,
// loop n=0..7; per-b partials into am_p (no atomics).
// ---------------------------------------------------------------------------
__global__ __launch_bounds__(512, 4) void am_v3(
    const __bf16* __restrict__ qb_, const __bf16* __restrict__ kvb,
    const __bf16* __restrict__ relb, const float* __restrict__ pbu,
    const float* __restrict__ pbv, const float* __restrict__ indice,
    const float* __restrict__ ml, float* __restrict__ am_p)
{
  __shared__ __align__(16) __bf16 bdl[160][33];
  __shared__ __align__(16) float Lt[32][132];

  const int bid = blockIdx.x;
  const int wrk = ((bid & 7) << 7) + (bid >> 3);
  const int bx = wrk & 15;
  const int by = (wrk >> 4) & 15;
  const int b  = wrk >> 8;
  const int tb = bx << 7, i0 = by << 5;
  const int tid = threadIdx.x;
  const int w = tid >> 6;
  const int l = tid & 63;
  const int li = l & 15;
  const int lq = l >> 4;

  float* outb = am_p + (size_t)b * 1048576;

  if (tb > 1536 + i0 + 31) {   // fully masked slice -> zeros
#pragma unroll
    for (int c = 0; c < 2; ++c) {
      const int e = c * 512 + tid;
      const int iloc = e >> 5, tq = e & 31;
      f32x4 z = {0.f, 0.f, 0.f, 0.f};
      *(f32x4*)(outb + (size_t)(i0 + iloc) * 2048 + tb + tq * 4) = z;
    }
    return;
  }
  const int rb = tb + 480 - i0;
  float acc[2][4] = {};

  for (int nn = 0; nn < 8; ++nn) {
    const int plane = b * 8 + nn;
    const __bf16* kbase = kvb + (size_t)b * 1024 + nn * 64;
    const __bf16* rbase = relb + (size_t)b * 512 + nn * 64;
    bhalf8 qu[2][2], qv[2][2];
    float g[2][4], mrow[2], rl[2];
#pragma unroll
    for (int it = 0; it < 2; ++it) {
      const int i = i0 + it * 16 + li;
      const float* gp = indice + ((size_t)i * 4 + b) * 4;
      g[it][0] = gp[0]; g[it][1] = gp[1]; g[it][2] = gp[2]; g[it][3] = gp[3];
      const float* mp = ml + ((size_t)plane * 512 + i) * 2;
      mrow[it] = mp[0]; rl[it] = 1.f / mp[1];
#pragma unroll
      for (int h = 0; h < 2; ++h) {
        const int dc = h * 32 + lq * 8;
        bhalf8 q8 = *(const bhalf8*)(qb_ + ((size_t)i * 4 + b) * 512 + nn * 64 + dc);
        float ub[8], vb[8];
        *(float4*)&ub[0] = *(const float4*)(pbu + nn * 64 + dc);
        *(float4*)&ub[4] = *(const float4*)(pbu + nn * 64 + dc + 4);
        *(float4*)&vb[0] = *(const float4*)(pbv + nn * 64 + dc);
        *(float4*)&vb[4] = *(const float4*)(pbv + nn * 64 + dc + 4);
        bhalf8 a, c;
#pragma unroll
        for (int j = 0; j < 8; ++j) {
          const float qf = (float)q8[j];
          a[j] = (__bf16)(qf + ub[j]);
          c[j] = (__bf16)(qf + vb[j]);
        }
        qu[it][h] = a; qv[it][h] = c;
      }
    }
    // BD
#pragma unroll
    for (int ri = 0; ri < 2; ++ri) {
      const int rs = w + ri * 8;
      if (ri == 0 || rs < 10) {
        int row = rb + rs * 16 + li;
        row = row > 2047 ? 2047 : row;
        const __bf16* rp = rbase + (size_t)row * 2048;
        bhalf8 a0 = *(const bhalf8*)(rp + lq * 8);
        bhalf8 a1 = *(const bhalf8*)(rp + 32 + lq * 8);
#pragma unroll
        for (int it = 0; it < 2; ++it) {
          f32x4 c = {0.f, 0.f, 0.f, 0.f};
          c = MFMA16(a0, qv[it][0], c);
          c = MFMA16(a1, qv[it][1], c);
#pragma unroll
          for (int r = 0; r < 4; ++r) {
            const int rowl = rs * 16 + lq * 4 + r;
            int rk = (rb + rowl) >> 9; rk = rk > 3 ? 3 : rk;
            bdl[rowl][it * 16 + li] = (__bf16)(c[r] * g[it][rk]);
          }
        }
      }
    }
    // AC
    f32x4 s[2];
    {
      const __bf16* kp = kbase + (size_t)(tb + w * 16 + li) * 4096;
      bhalf8 a0 = *(const bhalf8*)(kp + lq * 8);
      bhalf8 a1 = *(const bhalf8*)(kp + 32 + lq * 8);
#pragma unroll
      for (int it = 0; it < 2; ++it) {
        f32x4 c = {0.f, 0.f, 0.f, 0.f};
        c = MFMA16(a0, qu[it][0], c);
        c = MFMA16(a1, qu[it][1], c);
        s[it] = c;
      }
    }
    __syncthreads();   // bd visible
#pragma unroll
    for (int it = 0; it < 2; ++it) {
      const int i = i0 + it * 16 + li;
#pragma unroll
      for (int r = 0; r < 4; ++r) {
        const int tl = w * 16 + lq * 4 + r;
        const int t = tb + tl;
        if (t <= 1536 + i) {
          const float bdv = (float)bdl[tl + 31 - it * 16 - li][it * 16 + li];
          const float sc = (s[it][r] * g[it][t >> 9] + bdv) * 0.125f;
          acc[it][r] += __expf(sc - mrow[it]) * rl[it];
        }
      }
    }
    __syncthreads();   // protect bdl before next plane
  }
  // coalesced writeback via LDS
#pragma unroll
  for (int it = 0; it < 2; ++it)
#pragma unroll
    for (int r = 0; r < 4; ++r)
      Lt[it * 16 + li][w * 16 + lq * 4 + r] = acc[it][r] * 0.03125f;
  __syncthreads();
#pragma unroll
  for (int c = 0; c < 2; ++c) {
    const int e = c * 512 + tid;
    const int iloc = e >> 5, tq = e & 31;
    f32x4 v = *(f32x4*)&Lt[iloc][tq * 4];
    *(f32x4*)(outb + (size_t)(i0 + iloc) * 2048 + tb + tq * 4) = v;
  }
}

// ---------------------------------------------------------------------------
// am = sum of 4 per-b partials
// ---------------------------------------------------------------------------
__global__ __launch_bounds__(256) void am_reduce(const float* __restrict__ am_p,
                                                 float* __restrict__ am)
{
  const size_t i = ((size_t)blockIdx.x * 256 + threadIdx.x) * 4;
  f32x4 v = *(const f32x4*)(am_p + i);
  v += *(const f32x4*)(am_p + 1048576 + i);
  v += *(const f32x4*)(am_p + 2097152 + i);
  v += *(const f32x4*)(am_p + 3145728 + i);
  *(f32x4*)(am + i) = v;
}

// ---------------------------------------------------------------------------
// Residual + LayerNorm
// ---------------------------------------------------------------------------
__global__ __launch_bounds__(256) void ln_f32(
    const float* __restrict__ x, const float* __restrict__ ao,
    const float* __restrict__ g, const float* __restrict__ bb,
    float* __restrict__ out)
{
  const int row = blockIdx.x;
  const int tid = threadIdx.x;
  const size_t base = (size_t)row * 512;
  const float y0 = x[base + tid] + ao[base + tid];
  const float y1 = x[base + 256 + tid] + ao[base + 256 + tid];
  float s  = y0 + y1;
  float ss = y0 * y0 + y1 * y1;
#pragma unroll
  for (int off = 32; off > 0; off >>= 1) {
    s  += __shfl_xor(s, off);
    ss += __shfl_xor(ss, off);
  }
  __shared__ float sred[4], ssred[4], stat[2];
  const int w = tid >> 6;
  if ((tid & 63) == 0) { sred[w] = s; ssred[w] = ss; }
  __syncthreads();
  if (tid == 0) {
    const float S  = sred[0] + sred[1] + sred[2] + sred[3];
    const float SS = ssred[0] + ssred[1] + ssred[2] + ssred[3];
    const float mu = S * (1.f / 512.f);
    const float var = SS * (1.f / 512.f) - mu * mu;
    stat[0] = mu;
    stat[1] = rsqrtf(var + 1e-5f);
  }
  __syncthreads();
  const float mu = stat[0], rs = stat[1];
  out[base + tid]       = (y0 - mu) * rs * g[tid] + bb[tid];
  out[base + 256 + tid] = (y1 - mu) * rs * g[256 + tid] + bb[256 + tid];
}

// ---------------------------------------------------------------------------
// Launch. ws layout (bf16 elems unless noted):
//   cb    @ 0          4,194,304   -> becomes vtb (V^T) after kv GEMM
//   posb  @ 4,194,304  4,194,304   -> (cb+posb) become am_p (4x1M f32) for am
//   qb    @ 8,388,608  1,048,576
//   kvb   @ 9,437,184  8,388,608
//   relb  @ 17,825,792 4,194,304
//   vecb  @ 22,020,096 1,048,576
//   wqt/wkvt/wrelt/wot @ 23,068,672 .. 24,379,392
//   aof f32 @ byte 48,758,784 (1M f32), ml f32 after (32K f32) -> ~53.1 MB
// ---------------------------------------------------------------------------
extern "C" void kernel_launch(void* const* d_in, const int* in_sizes, int n_in,
                              void* d_out, int out_size, void* d_ws, size_t ws_size,
                              hipStream_t stream)
{
  (void)in_sizes; (void)n_in; (void)out_size; (void)ws_size;
  const float* x      = (const float*)d_in[0];
  const float* memory = (const float*)d_in[1];
  const float* pos    = (const float*)d_in[2];
  const float* pbu    = (const float*)d_in[3];
  const float* pbv    = (const float*)d_in[4];
  const float* indice = (const float*)d_in[6];
  const float* W_q    = (const float*)d_in[7];
  const float* W_kv   = (const float*)d_in[8];
  const float* W_rel  = (const float*)d_in[9];
  const float* W_o    = (const float*)d_in[10];
  const float* ln_g   = (const float*)d_in[11];
  const float* ln_b   = (const float*)d_in[12];

  float* out = (float*)d_out;
  float* am  = out + 1048576;

  __bf16* cb    = (__bf16*)d_ws;
  __bf16* posb  = cb + 4194304;
  __bf16* qb    = posb + 4194304;
  __bf16* kvb   = qb + 1048576;
  __bf16* relb  = kvb + 8388608;
  __bf16* vecb  = relb + 4194304;
  __bf16* wqt   = vecb + 1048576;
  __bf16* wkvt  = wqt + 262144;
  __bf16* wrelt = wkvt + 524288;
  __bf16* wot   = wrelt + 262144;
  float*  aof   = (float*)(wot + 262144);
  float*  ml    = aof + 1048576;
  __bf16* xb    = cb + 3145728;          // x rows start at row 6144
  __bf16* vtb   = cb;                    // reuses cb after kv GEMM
  float*  am_p  = (float*)d_ws;          // reuses cb+posb after attn

  cast_bf16<<<3072, 256, 0, stream>>>(memory, cb, 786432);
  cast_bf16<<<1024, 256, 0, stream>>>(x, xb, 262144);
  cast_bf16<<<4096, 256, 0, stream>>>(pos, posb, 1048576);
  transcast<<<dim3(8, 128), 256, 0, stream>>>(W_q,   wqt,   512, 512);
  transcast<<<dim3(8, 256), 256, 0, stream>>>(W_kv,  wkvt,  512, 1024);
  transcast<<<dim3(8, 128), 256, 0, stream>>>(W_rel, wrelt, 512, 512);
  transcast<<<dim3(8, 128), 256, 0, stream>>>(W_o,   wot,   512, 512);

  gemm_bf16<0><<<dim3(16, 4), 256, 0, stream>>>(xb,   wqt,  qb,  2048, 512, 512);
  gemm_bf16<0><<<dim3(64, 8), 256, 0, stream>>>(cb,   wkvt, kvb, 8192, 1024, 512);
  gemm_bf16<0><<<dim3(64, 4), 256, 0, stream>>>(posb, wrelt, relb, 8192, 512, 512);

  vtrans<<<dim3(32, 32), 256, 0, stream>>>(kvb, vtb);

  attn_v3<<<512, 512, 0, stream>>>(qb, kvb, relb, vtb, pbu, pbv, indice, vecb, ml);

  am_v3<<<1024, 512, 0, stream>>>(qb, kvb, relb, pbu, pbv, indice, ml, am_p);
  am_reduce<<<1024, 256, 0, stream>>>(am_p, am);

  gemm_bf16<1><<<dim3(16, 4), 256, 0, stream>>>(vecb, wot, aof, 2048, 512, 512);
  ln_f32<<<2048, 256, 0, stream>>>(x, aof, ln_g, ln_b, out);
}